// Round 6
// baseline (915.744 us; speedup 1.0000x reference)
//
#include <hip/hip_runtime.h>

#define N_NODES 100000
#define N_EDGES 1600000
#define NWIN 1024
#define WN 98                      // nodes per window; 1024*98 = 100352 >= N
#define CB ((N_EDGES + 4095) / 4096)    // 391 count blocks
#define FB ((N_EDGES + 16383) / 16384)  // 98 fill blocks
#define NTILES ((N_NODES + 63) / 64)    // 1563 row tiles of 64

__device__ __forceinline__ void fma4(float4& a, float s, const float4& w) {
  a.x = fmaf(s, w.x, a.x);
  a.y = fmaf(s, w.y, a.y);
  a.z = fmaf(s, w.z, a.z);
  a.w = fmaf(s, w.w, a.w);
}

// ---------------------------------------------------------------------------
// Fused GEMM0+GEMM1 (h kept in LDS, never hits global):
//   phase 1: h = relu(Wr0@x + Wl0@aggx + bl0*(deg>0))
//   phase 2: h1 = h@Wl1.T + bl1 ; hr1 = h@Wr1.T
// ---------------------------------------------------------------------------
__global__ __launch_bounds__(256) void gemm01_kernel(
    const float* __restrict__ X, const float* __restrict__ AGG,
    const float* __restrict__ Wr0, const float* __restrict__ Wl0,
    const float* __restrict__ bl0, const unsigned* __restrict__ deg,
    const float* __restrict__ Wl1, const float* __restrict__ bl1,
    const float* __restrict__ Wr1, float* __restrict__ H1,
    float* __restrict__ HR1) {
  __shared__ float sW[128][68];
  __shared__ float sX[64][68];
  const int t = threadIdx.x;
  const int rbase = blockIdx.x * 64;

  for (int idx = t; idx < 64 * 64; idx += 256) {
    const int c = idx >> 6, k = idx & 63;
    sW[k][c] = Wr0[idx];
    sW[k + 64][c] = Wl0[idx];
  }

  const int tc = t & 15, tr = t >> 4;
  const int c0 = tc * 4, r0 = tr * 4;
  float4 acc0 = {0, 0, 0, 0}, acc1 = {0, 0, 0, 0};
  float4 acc2 = {0, 0, 0, 0}, acc3 = {0, 0, 0, 0};

  const float* bufs[2] = {X, AGG};
  for (int half = 0; half < 2; ++half) {
    if (half) __syncthreads();
    const float4* __restrict__ B4 = (const float4*)bufs[half];
    for (int f = t; f < 1024; f += 256) {
      const int row = f >> 4, kq = f & 15;
      const int grow = rbase + row;
      float4 v = {0, 0, 0, 0};
      if (grow < N_NODES) v = B4[(size_t)grow * 16 + kq];
      *(float4*)&sX[row][kq * 4] = v;
    }
    __syncthreads();
    const int kb = half * 64;
#pragma unroll 4
    for (int kc = 0; kc < 64; kc += 4) {
      float4 x0 = *(const float4*)&sX[r0 + 0][kc];
      float4 x1 = *(const float4*)&sX[r0 + 1][kc];
      float4 x2 = *(const float4*)&sX[r0 + 2][kc];
      float4 x3 = *(const float4*)&sX[r0 + 3][kc];
      float4 w0 = *(const float4*)&sW[kb + kc + 0][c0];
      float4 w1 = *(const float4*)&sW[kb + kc + 1][c0];
      float4 w2 = *(const float4*)&sW[kb + kc + 2][c0];
      float4 w3 = *(const float4*)&sW[kb + kc + 3][c0];
      fma4(acc0, x0.x, w0); fma4(acc0, x0.y, w1); fma4(acc0, x0.z, w2); fma4(acc0, x0.w, w3);
      fma4(acc1, x1.x, w0); fma4(acc1, x1.y, w1); fma4(acc1, x1.z, w2); fma4(acc1, x1.w, w3);
      fma4(acc2, x2.x, w0); fma4(acc2, x2.y, w1); fma4(acc2, x2.z, w2); fma4(acc2, x2.w, w3);
      fma4(acc3, x3.x, w0); fma4(acc3, x3.y, w1); fma4(acc3, x3.z, w2); fma4(acc3, x3.w, w3);
    }
  }

  __syncthreads();
  {
    const float4 bias = *(const float4*)&bl0[c0];
    float4 accs[4] = {acc0, acc1, acc2, acc3};
#pragma unroll
    for (int i = 0; i < 4; ++i) {
      const int grow = rbase + r0 + i;
      const float g = (grow < N_NODES && deg[grow] > 0) ? 1.0f : 0.0f;
      float4 r;
      r.x = fmaxf(accs[i].x + bias.x * g, 0.0f);
      r.y = fmaxf(accs[i].y + bias.y * g, 0.0f);
      r.z = fmaxf(accs[i].z + bias.z * g, 0.0f);
      r.w = fmaxf(accs[i].w + bias.w * g, 0.0f);
      *(float4*)&sX[r0 + i][c0] = r;
    }
  }
  for (int idx = t; idx < 32 * 64; idx += 256) {
    const int c = idx >> 6, k = idx & 63;
    sW[k][c] = Wl1[idx];
    sW[k][c + 32] = Wr1[idx];
  }
  __syncthreads();

  acc0 = {0, 0, 0, 0}; acc1 = {0, 0, 0, 0};
  acc2 = {0, 0, 0, 0}; acc3 = {0, 0, 0, 0};
#pragma unroll 4
  for (int kc = 0; kc < 64; kc += 4) {
    float4 x0 = *(const float4*)&sX[r0 + 0][kc];
    float4 x1 = *(const float4*)&sX[r0 + 1][kc];
    float4 x2 = *(const float4*)&sX[r0 + 2][kc];
    float4 x3 = *(const float4*)&sX[r0 + 3][kc];
    float4 w0 = *(const float4*)&sW[kc + 0][c0];
    float4 w1 = *(const float4*)&sW[kc + 1][c0];
    float4 w2 = *(const float4*)&sW[kc + 2][c0];
    float4 w3 = *(const float4*)&sW[kc + 3][c0];
    fma4(acc0, x0.x, w0); fma4(acc0, x0.y, w1); fma4(acc0, x0.z, w2); fma4(acc0, x0.w, w3);
    fma4(acc1, x1.x, w0); fma4(acc1, x1.y, w1); fma4(acc1, x1.z, w2); fma4(acc1, x1.w, w3);
    fma4(acc2, x2.x, w0); fma4(acc2, x2.y, w1); fma4(acc2, x2.z, w2); fma4(acc2, x2.w, w3);
    fma4(acc3, x3.x, w0); fma4(acc3, x3.y, w1); fma4(acc3, x3.z, w2); fma4(acc3, x3.w, w3);
  }

  const bool left = c0 < 32;
  float4 bias = {0, 0, 0, 0};
  if (left) bias = *(const float4*)&bl1[c0];
  float4 accs[4] = {acc0, acc1, acc2, acc3};
#pragma unroll
  for (int i = 0; i < 4; ++i) {
    const int grow = rbase + r0 + i;
    if (grow < N_NODES) {
      float4 r;
      r.x = accs[i].x + bias.x;
      r.y = accs[i].y + bias.y;
      r.z = accs[i].z + bias.z;
      r.w = accs[i].w + bias.w;
      if (left)
        ((float4*)H1)[(size_t)grow * 8 + tc] = r;
      else
        ((float4*)HR1)[(size_t)grow * 8 + (tc - 8)] = r;
    }
  }
}

// ---------------------------------------------------------------------------
// Edge bucketing by dst window (1024 windows of 98 nodes). No per-node CSR.
// ---------------------------------------------------------------------------
__global__ __launch_bounds__(256) void bucket_count(const int* __restrict__ ei,
                                                    unsigned* __restrict__ bcnt) {
  __shared__ unsigned h[NWIN];
  const int t = threadIdx.x;
  for (int i = t; i < NWIN; i += 256) h[i] = 0;
  __syncthreads();
  const long long base = (long long)blockIdx.x * 4096;
#pragma unroll
  for (int i = 0; i < 16; ++i) {
    const long long e = base + i * 256 + t;
    if (e < N_EDGES) {
      const unsigned d = (unsigned)ei[N_EDGES + e];
      atomicAdd(&h[d / WN], 1u);
    }
  }
  __syncthreads();
  for (int i = t; i < NWIN; i += 256) {
    const unsigned c = h[i];
    if (c) atomicAdd(&bcnt[i], c);
  }
}

__global__ __launch_bounds__(1024) void bucket_scan(
    const unsigned* __restrict__ bcnt, unsigned* __restrict__ bbase,
    unsigned* __restrict__ bcursor) {
  __shared__ unsigned s[NWIN];
  const int t = threadIdx.x;
  const unsigned v = bcnt[t];
  s[t] = v;
  __syncthreads();
  for (int off = 1; off < NWIN; off <<= 1) {
    const unsigned u = (t >= off) ? s[t - off] : 0u;
    __syncthreads();
    s[t] += u;
    __syncthreads();
  }
  const unsigned ex = s[t] - v;
  bbase[t] = ex;
  bcursor[t] = ex;
  if (t == NWIN - 1) bbase[NWIN] = s[NWIN - 1];
}

// 16384 edges/block: per-block LDS histogram -> bulk cursor reservation ->
// packed (dstl<<24|src) writes in ~16-entry contiguous chunks per bucket.
__global__ __launch_bounds__(256) void bucket_fill(const int* __restrict__ ei,
                                                   unsigned* __restrict__ bcursor,
                                                   unsigned* __restrict__ ebuf) {
  __shared__ unsigned lcnt[NWIN], gbase[NWIN];
  const int t = threadIdx.x;
  for (int i = t; i < NWIN; i += 256) lcnt[i] = 0;
  __syncthreads();
  const long long base = (long long)blockIdx.x * 16384;
#pragma unroll 4
  for (int i = 0; i < 64; ++i) {
    const long long e = base + i * 256 + t;
    if (e < N_EDGES) {
      const unsigned d = (unsigned)ei[N_EDGES + e];
      atomicAdd(&lcnt[d / WN], 1u);
    }
  }
  __syncthreads();
  for (int i = t; i < NWIN; i += 256) {
    const unsigned c = lcnt[i];
    gbase[i] = c ? atomicAdd(&bcursor[i], c) : 0u;
    lcnt[i] = 0;  // reused as local index
  }
  __syncthreads();
#pragma unroll 4
  for (int i = 0; i < 64; ++i) {
    const long long e = base + i * 256 + t;
    if (e < N_EDGES) {
      const unsigned s = (unsigned)ei[e];
      const unsigned d = (unsigned)ei[N_EDGES + e];
      const unsigned b = d / WN, dl = d - b * WN;
      const unsigned off = atomicAdd(&lcnt[b], 1u);
      ebuf[gbase[b] + off] = (dl << 24) | s;
    }
  }
}

// ---------------------------------------------------------------------------
// Windowed-LDS aggregation, layer 0: acc[98][64] in LDS, ds_add_f32 atomics.
// One wave handles one edge (64-lane row read), 2-deep unrolled.
// Epilogue: aggx = acc/deg (0 if isolated), deg written out.
// ---------------------------------------------------------------------------
__global__ __launch_bounds__(256) void agg0_win(
    const float* __restrict__ X, const unsigned* __restrict__ ebuf,
    const unsigned* __restrict__ bbase, float* __restrict__ aggx,
    unsigned* __restrict__ deg) {
  __shared__ float acc[WN * 64];
  __shared__ unsigned cnt[WN];
  const int t = threadIdx.x, w = blockIdx.x;
  const int lo = w * WN;
  for (int i = t; i < WN * 16; i += 256) ((float4*)acc)[i] = {0, 0, 0, 0};
  for (int i = t; i < WN; i += 256) cnt[i] = 0;
  __syncthreads();
  const unsigned beg = bbase[w], end = bbase[w + 1];
  const int wv = t >> 6, lane = t & 63;
  unsigned e = beg + wv;
  for (; e + 4 < end; e += 8) {
    const unsigned p0 = ebuf[e], p1 = ebuf[e + 4];
    const float v0 = X[(size_t)(p0 & 0xFFFFFFu) * 64 + lane];
    const float v1 = X[(size_t)(p1 & 0xFFFFFFu) * 64 + lane];
    atomicAdd(&acc[(p0 >> 24) * 64 + lane], v0);
    atomicAdd(&acc[(p1 >> 24) * 64 + lane], v1);
    if (!lane) {
      atomicAdd(&cnt[p0 >> 24], 1u);
      atomicAdd(&cnt[p1 >> 24], 1u);
    }
  }
  for (; e < end; e += 4) {
    const unsigned p = ebuf[e];
    const float v = X[(size_t)(p & 0xFFFFFFu) * 64 + lane];
    atomicAdd(&acc[(p >> 24) * 64 + lane], v);
    if (!lane) atomicAdd(&cnt[p >> 24], 1u);
  }
  __syncthreads();
  for (int idx = t; idx < WN * 16; idx += 256) {
    const int nl = idx >> 4, q = idx & 15;
    const int node = lo + nl;
    if (node < N_NODES) {
      const unsigned c = cnt[nl];
      const float inv = c ? 1.0f / (float)c : 0.0f;
      float4 v = *(float4*)&acc[nl * 64 + q * 4];
      v.x *= inv; v.y *= inv; v.z *= inv; v.w *= inv;
      ((float4*)aggx)[(size_t)node * 16 + q] = v;
      if (!q) deg[node] = c;
    }
  }
}

// ---------------------------------------------------------------------------
// Windowed-LDS aggregation, layer 1 (F=32): 2 edges per wave per step.
// Epilogue fuses: out = acc/deg + hr1.
// ---------------------------------------------------------------------------
__global__ __launch_bounds__(256) void agg1_win(
    const float* __restrict__ H1, const unsigned* __restrict__ ebuf,
    const unsigned* __restrict__ bbase, const unsigned* __restrict__ deg,
    const float* __restrict__ HR1, float* __restrict__ outp) {
  __shared__ float acc[WN * 32];
  const int t = threadIdx.x, w = blockIdx.x;
  const int lo = w * WN;
  for (int i = t; i < WN * 8; i += 256) ((float4*)acc)[i] = {0, 0, 0, 0};
  __syncthreads();
  const unsigned beg = bbase[w], end = bbase[w + 1];
  const int wv = t >> 6, lane = t & 63;
  const int f = lane & 31, sub = lane >> 5;
  unsigned e = beg + wv * 2 + sub;
  for (; e + 8 < end; e += 16) {
    const unsigned p0 = ebuf[e], p1 = ebuf[e + 8];
    const float v0 = H1[(size_t)(p0 & 0xFFFFFFu) * 32 + f];
    const float v1 = H1[(size_t)(p1 & 0xFFFFFFu) * 32 + f];
    atomicAdd(&acc[(p0 >> 24) * 32 + f], v0);
    atomicAdd(&acc[(p1 >> 24) * 32 + f], v1);
  }
  for (; e < end; e += 8) {
    const unsigned p = ebuf[e];
    const float v = H1[(size_t)(p & 0xFFFFFFu) * 32 + f];
    atomicAdd(&acc[(p >> 24) * 32 + f], v);
  }
  __syncthreads();
  for (int idx = t; idx < WN * 8; idx += 256) {
    const int nl = idx >> 3, q = idx & 7;
    const int node = lo + nl;
    if (node < N_NODES) {
      const unsigned c = deg[node];
      const float inv = c ? 1.0f / (float)c : 0.0f;
      float4 v = *(float4*)&acc[nl * 32 + q * 4];
      const float4 b = ((const float4*)HR1)[(size_t)node * 8 + q];
      v.x = v.x * inv + b.x;
      v.y = v.y * inv + b.y;
      v.z = v.z * inv + b.z;
      v.w = v.w * inv + b.w;
      ((float4*)outp)[(size_t)node * 8 + q] = v;
    }
  }
}

extern "C" void kernel_launch(void* const* d_in, const int* in_sizes, int n_in,
                              void* d_out, int out_size, void* d_ws,
                              size_t ws_size, hipStream_t stream) {
  const float* x = (const float*)d_in[0];
  const int* ei = (const int*)d_in[1];
  const float* Wl0 = (const float*)d_in[2];
  const float* bl0 = (const float*)d_in[3];
  const float* Wr0 = (const float*)d_in[4];
  const float* Wl1 = (const float*)d_in[5];
  const float* bl1 = (const float*)d_in[6];
  const float* Wr1 = (const float*)d_in[7];
  float* out = (float*)d_out;

  const int N = N_NODES;

  // Workspace:
  //   aggx : N*64 f32
  //   bufB : h1 [N,32] + hr1 [N,32]
  //   deg[N], bcnt[1024], bbase[1025], bcursor[1024], ebuf[E] : u32
  float* aggx = (float*)d_ws;
  float* bufB = aggx + (size_t)N * 64;
  unsigned* deg = (unsigned*)(bufB + (size_t)N * 64);
  unsigned* bcnt = deg + N;
  unsigned* bbase = bcnt + NWIN;
  unsigned* bcursor = bbase + (NWIN + 1);
  unsigned* ebuf = bcursor + NWIN;
  float* h1 = bufB;
  float* hr1 = bufB + (size_t)N * 32;

  hipMemsetAsync(bcnt, 0, NWIN * sizeof(unsigned), stream);

  const dim3 blk(256);

  // ---- edge bucketing (graph identical for both layers) ----
  bucket_count<<<CB, blk, 0, stream>>>(ei, bcnt);
  bucket_scan<<<1, NWIN, 0, stream>>>(bcnt, bbase, bcursor);
  bucket_fill<<<FB, blk, 0, stream>>>(ei, bcursor, ebuf);

  // ---- layer-0 aggregation: aggx = mean(x[src]), deg ----
  agg0_win<<<NWIN, blk, 0, stream>>>(x, ebuf, bbase, aggx, deg);

  // ---- fused GEMMs: h in LDS; emits h1 = h@Wl1.T+bl1, hr1 = h@Wr1.T ----
  gemm01_kernel<<<NTILES, blk, 0, stream>>>(x, aggx, Wr0, Wl0, bl0, deg, Wl1,
                                            bl1, Wr1, h1, hr1);

  // ---- layer-1 aggregation + combine: out = mean(h1[src]) + hr1 ----
  agg1_win<<<NWIN, blk, 0, stream>>>(h1, ebuf, bbase, deg, hr1, out);
}

// Round 7
// 224.638 us; speedup vs baseline: 4.0765x; 4.0765x over previous
//
#include <hip/hip_runtime.h>

#define N_NODES 100000
#define N_EDGES 1600000
#define NWIN 1024
#define WN 98                           // nodes per window; 1024*98 >= N
#define WCAP 4096                       // max edges per window (mean 1562, 60+ sigma)
#define CB ((N_EDGES + 4095) / 4096)    // 391 count blocks
#define FB ((N_EDGES + 16383) / 16384)  // 98 fill blocks
#define NTILES ((N_NODES + 63) / 64)    // 1563 row tiles of 64

__device__ __forceinline__ void fma4(float4& a, float s, const float4& w) {
  a.x = fmaf(s, w.x, a.x);
  a.y = fmaf(s, w.y, a.y);
  a.z = fmaf(s, w.z, a.z);
  a.w = fmaf(s, w.w, a.w);
}

// ---------------------------------------------------------------------------
// Fused GEMM0+GEMM1 (h kept in LDS, never hits global):
//   phase 1: h = relu(Wr0@x + Wl0@aggx + bl0*(deg>0))
//   phase 2: h1 = h@Wl1.T + bl1 ; hr1 = h@Wr1.T
// ---------------------------------------------------------------------------
__global__ __launch_bounds__(256) void gemm01_kernel(
    const float* __restrict__ X, const float* __restrict__ AGG,
    const float* __restrict__ Wr0, const float* __restrict__ Wl0,
    const float* __restrict__ bl0, const unsigned* __restrict__ deg,
    const float* __restrict__ Wl1, const float* __restrict__ bl1,
    const float* __restrict__ Wr1, float* __restrict__ H1,
    float* __restrict__ HR1) {
  __shared__ float sW[128][68];
  __shared__ float sX[64][68];
  const int t = threadIdx.x;
  const int rbase = blockIdx.x * 64;

  for (int idx = t; idx < 64 * 64; idx += 256) {
    const int c = idx >> 6, k = idx & 63;
    sW[k][c] = Wr0[idx];
    sW[k + 64][c] = Wl0[idx];
  }

  const int tc = t & 15, tr = t >> 4;
  const int c0 = tc * 4, r0 = tr * 4;
  float4 acc0 = {0, 0, 0, 0}, acc1 = {0, 0, 0, 0};
  float4 acc2 = {0, 0, 0, 0}, acc3 = {0, 0, 0, 0};

  const float* bufs[2] = {X, AGG};
  for (int half = 0; half < 2; ++half) {
    if (half) __syncthreads();
    const float4* __restrict__ B4 = (const float4*)bufs[half];
    for (int f = t; f < 1024; f += 256) {
      const int row = f >> 4, kq = f & 15;
      const int grow = rbase + row;
      float4 v = {0, 0, 0, 0};
      if (grow < N_NODES) v = B4[(size_t)grow * 16 + kq];
      *(float4*)&sX[row][kq * 4] = v;
    }
    __syncthreads();
    const int kb = half * 64;
#pragma unroll 4
    for (int kc = 0; kc < 64; kc += 4) {
      float4 x0 = *(const float4*)&sX[r0 + 0][kc];
      float4 x1 = *(const float4*)&sX[r0 + 1][kc];
      float4 x2 = *(const float4*)&sX[r0 + 2][kc];
      float4 x3 = *(const float4*)&sX[r0 + 3][kc];
      float4 w0 = *(const float4*)&sW[kb + kc + 0][c0];
      float4 w1 = *(const float4*)&sW[kb + kc + 1][c0];
      float4 w2 = *(const float4*)&sW[kb + kc + 2][c0];
      float4 w3 = *(const float4*)&sW[kb + kc + 3][c0];
      fma4(acc0, x0.x, w0); fma4(acc0, x0.y, w1); fma4(acc0, x0.z, w2); fma4(acc0, x0.w, w3);
      fma4(acc1, x1.x, w0); fma4(acc1, x1.y, w1); fma4(acc1, x1.z, w2); fma4(acc1, x1.w, w3);
      fma4(acc2, x2.x, w0); fma4(acc2, x2.y, w1); fma4(acc2, x2.z, w2); fma4(acc2, x2.w, w3);
      fma4(acc3, x3.x, w0); fma4(acc3, x3.y, w1); fma4(acc3, x3.z, w2); fma4(acc3, x3.w, w3);
    }
  }

  __syncthreads();
  {
    const float4 bias = *(const float4*)&bl0[c0];
    float4 accs[4] = {acc0, acc1, acc2, acc3};
#pragma unroll
    for (int i = 0; i < 4; ++i) {
      const int grow = rbase + r0 + i;
      const float g = (grow < N_NODES && deg[grow] > 0) ? 1.0f : 0.0f;
      float4 r;
      r.x = fmaxf(accs[i].x + bias.x * g, 0.0f);
      r.y = fmaxf(accs[i].y + bias.y * g, 0.0f);
      r.z = fmaxf(accs[i].z + bias.z * g, 0.0f);
      r.w = fmaxf(accs[i].w + bias.w * g, 0.0f);
      *(float4*)&sX[r0 + i][c0] = r;
    }
  }
  for (int idx = t; idx < 32 * 64; idx += 256) {
    const int c = idx >> 6, k = idx & 63;
    sW[k][c] = Wl1[idx];
    sW[k][c + 32] = Wr1[idx];
  }
  __syncthreads();

  acc0 = {0, 0, 0, 0}; acc1 = {0, 0, 0, 0};
  acc2 = {0, 0, 0, 0}; acc3 = {0, 0, 0, 0};
#pragma unroll 4
  for (int kc = 0; kc < 64; kc += 4) {
    float4 x0 = *(const float4*)&sX[r0 + 0][kc];
    float4 x1 = *(const float4*)&sX[r0 + 1][kc];
    float4 x2 = *(const float4*)&sX[r0 + 2][kc];
    float4 x3 = *(const float4*)&sX[r0 + 3][kc];
    float4 w0 = *(const float4*)&sW[kc + 0][c0];
    float4 w1 = *(const float4*)&sW[kc + 1][c0];
    float4 w2 = *(const float4*)&sW[kc + 2][c0];
    float4 w3 = *(const float4*)&sW[kc + 3][c0];
    fma4(acc0, x0.x, w0); fma4(acc0, x0.y, w1); fma4(acc0, x0.z, w2); fma4(acc0, x0.w, w3);
    fma4(acc1, x1.x, w0); fma4(acc1, x1.y, w1); fma4(acc1, x1.z, w2); fma4(acc1, x1.w, w3);
    fma4(acc2, x2.x, w0); fma4(acc2, x2.y, w1); fma4(acc2, x2.z, w2); fma4(acc2, x2.w, w3);
    fma4(acc3, x3.x, w0); fma4(acc3, x3.y, w1); fma4(acc3, x3.z, w2); fma4(acc3, x3.w, w3);
  }

  const bool left = c0 < 32;
  float4 bias = {0, 0, 0, 0};
  if (left) bias = *(const float4*)&bl1[c0];
  float4 accs[4] = {acc0, acc1, acc2, acc3};
#pragma unroll
  for (int i = 0; i < 4; ++i) {
    const int grow = rbase + r0 + i;
    if (grow < N_NODES) {
      float4 r;
      r.x = accs[i].x + bias.x;
      r.y = accs[i].y + bias.y;
      r.z = accs[i].z + bias.z;
      r.w = accs[i].w + bias.w;
      if (left)
        ((float4*)H1)[(size_t)grow * 8 + tc] = r;
      else
        ((float4*)HR1)[(size_t)grow * 8 + (tc - 8)] = r;
    }
  }
}

// ---------------------------------------------------------------------------
// Edge bucketing by dst window (1024 windows of 98 nodes).
// ---------------------------------------------------------------------------
__global__ __launch_bounds__(256) void bucket_count(const int* __restrict__ ei,
                                                    unsigned* __restrict__ bcnt) {
  __shared__ unsigned h[NWIN];
  const int t = threadIdx.x;
  for (int i = t; i < NWIN; i += 256) h[i] = 0;
  __syncthreads();
  const long long base = (long long)blockIdx.x * 4096;
#pragma unroll
  for (int i = 0; i < 16; ++i) {
    const long long e = base + i * 256 + t;
    if (e < N_EDGES) {
      const unsigned d = (unsigned)ei[N_EDGES + e];
      atomicAdd(&h[d / WN], 1u);
    }
  }
  __syncthreads();
  for (int i = t; i < NWIN; i += 256) {
    const unsigned c = h[i];
    if (c) atomicAdd(&bcnt[i], c);
  }
}

__global__ __launch_bounds__(1024) void bucket_scan(
    const unsigned* __restrict__ bcnt, unsigned* __restrict__ bbase,
    unsigned* __restrict__ bcursor) {
  __shared__ unsigned s[NWIN];
  const int t = threadIdx.x;
  const unsigned v = bcnt[t];
  s[t] = v;
  __syncthreads();
  for (int off = 1; off < NWIN; off <<= 1) {
    const unsigned u = (t >= off) ? s[t - off] : 0u;
    __syncthreads();
    s[t] += u;
    __syncthreads();
  }
  const unsigned ex = s[t] - v;
  bbase[t] = ex;
  bcursor[t] = ex;
  if (t == NWIN - 1) bbase[NWIN] = s[NWIN - 1];
}

// 16384 edges/block: per-block LDS histogram -> bulk cursor reservation ->
// packed (dl<<24|src) writes in contiguous per-bucket chunks.
__global__ __launch_bounds__(256) void bucket_fill(const int* __restrict__ ei,
                                                   unsigned* __restrict__ bcursor,
                                                   unsigned* __restrict__ ebuf) {
  __shared__ unsigned lcnt[NWIN], gbase[NWIN];
  const int t = threadIdx.x;
  for (int i = t; i < NWIN; i += 256) lcnt[i] = 0;
  __syncthreads();
  const long long base = (long long)blockIdx.x * 16384;
#pragma unroll 4
  for (int i = 0; i < 64; ++i) {
    const long long e = base + i * 256 + t;
    if (e < N_EDGES) {
      const unsigned d = (unsigned)ei[N_EDGES + e];
      atomicAdd(&lcnt[d / WN], 1u);
    }
  }
  __syncthreads();
  for (int i = t; i < NWIN; i += 256) {
    const unsigned c = lcnt[i];
    gbase[i] = c ? atomicAdd(&bcursor[i], c) : 0u;
    lcnt[i] = 0;  // reused as local cursor
  }
  __syncthreads();
#pragma unroll 4
  for (int i = 0; i < 64; ++i) {
    const long long e = base + i * 256 + t;
    if (e < N_EDGES) {
      const unsigned s = (unsigned)ei[e];
      const unsigned d = (unsigned)ei[N_EDGES + e];
      const unsigned b = d / WN, dl = d - b * WN;
      const unsigned off = atomicAdd(&lcnt[b], 1u);
      ebuf[gbase[b] + off] = (dl << 24) | s;
    }
  }
}

// ---------------------------------------------------------------------------
// Per-window counting sort (in LDS, in-place in ebuf) -> CSR order.
// Emits rowptr (beg+prefix) and deg from the histogram. Coalesced I/O only.
// ---------------------------------------------------------------------------
__global__ __launch_bounds__(256) void win_sort(unsigned* __restrict__ ebuf,
                                                const unsigned* __restrict__ bbase,
                                                unsigned* __restrict__ rowptr,
                                                unsigned* __restrict__ deg) {
  __shared__ unsigned earr[WCAP];
  __shared__ unsigned sorted[WCAP];
  __shared__ unsigned hist[WN], pre[WN + 1], cur[WN];
  const int t = threadIdx.x, w = blockIdx.x;
  const int lo = w * WN;
  const unsigned beg = bbase[w], end = bbase[w + 1];
  const int n = (int)(end - beg);
  for (int i = t; i < WN; i += 256) hist[i] = 0;
  __syncthreads();
  for (int i = t; i < n; i += 256) {
    const unsigned p = ebuf[beg + i];
    earr[i] = p;
    atomicAdd(&hist[p >> 24], 1u);
  }
  __syncthreads();
  if (t == 0) {
    unsigned run = 0;
    for (int i = 0; i < WN; ++i) {
      pre[i] = run;
      run += hist[i];
    }
    pre[WN] = run;
  }
  __syncthreads();
  for (int dl = t; dl < WN; dl += 256) {
    const int node = lo + dl;
    if (node <= N_NODES) rowptr[node] = beg + pre[dl];
    if (node < N_NODES) deg[node] = hist[dl];
    cur[dl] = pre[dl];
  }
  __syncthreads();
  for (int i = t; i < n; i += 256) {
    const unsigned p = earr[i];
    const unsigned pos = atomicAdd(&cur[p >> 24], 1u);
    sorted[pos] = p;
  }
  __syncthreads();
  for (int i = t; i < n; i += 256) ebuf[beg + i] = sorted[i];
}

// ---------------------------------------------------------------------------
// Gather-aggregate (mean) + optional base add: one wave per dst node.
// Edge entries are packed (dl<<24|src) -> src = p & 0xFFFFFF.
// ---------------------------------------------------------------------------
template <int F, bool HAS_BASE>
__global__ __launch_bounds__(256) void gather_comb(
    const float* __restrict__ H, const unsigned* __restrict__ rowptr,
    const unsigned* __restrict__ csr, const float* __restrict__ base_row,
    float* __restrict__ outp) {
  constexpr int G = F / 4;
  constexpr int NG = 64 / G;
  const int node = (int)((blockIdx.x * 256 + threadIdx.x) >> 6);
  const int lane = threadIdx.x & 63;
  if (node >= N_NODES) return;
  const int g = lane / G, q = lane % G;
  const unsigned beg = rowptr[node], end = rowptr[node + 1];
  const float inv = (end > beg) ? 1.0f / (float)(end - beg) : 0.0f;
  const float4* __restrict__ H4 = (const float4*)H;

  float4 a0 = {0.f, 0.f, 0.f, 0.f}, a1 = {0.f, 0.f, 0.f, 0.f};
  unsigned e = beg + g;
  for (; e + NG < end; e += 2 * NG) {
    const unsigned s0 = csr[e] & 0xFFFFFFu, s1 = csr[e + NG] & 0xFFFFFFu;
    const float4 v0 = H4[(size_t)s0 * G + q];
    const float4 v1 = H4[(size_t)s1 * G + q];
    a0.x += v0.x; a0.y += v0.y; a0.z += v0.z; a0.w += v0.w;
    a1.x += v1.x; a1.y += v1.y; a1.z += v1.z; a1.w += v1.w;
  }
  if (e < end) {
    const float4 v = H4[(size_t)(csr[e] & 0xFFFFFFu) * G + q];
    a0.x += v.x; a0.y += v.y; a0.z += v.z; a0.w += v.w;
  }
  float sx = a0.x + a1.x, sy = a0.y + a1.y;
  float sz = a0.z + a1.z, sw = a0.w + a1.w;
#pragma unroll
  for (int m = G; m < 64; m <<= 1) {
    sx += __shfl_xor(sx, m, 64);
    sy += __shfl_xor(sy, m, 64);
    sz += __shfl_xor(sz, m, 64);
    sw += __shfl_xor(sw, m, 64);
  }
  if (g == 0) {
    float4 r;
    r.x = sx * inv; r.y = sy * inv; r.z = sz * inv; r.w = sw * inv;
    if (HAS_BASE) {
      const float4 b = ((const float4*)base_row)[(size_t)node * G + q];
      r.x += b.x; r.y += b.y; r.z += b.z; r.w += b.w;
    }
    ((float4*)outp)[(size_t)node * G + q] = r;
  }
}

extern "C" void kernel_launch(void* const* d_in, const int* in_sizes, int n_in,
                              void* d_out, int out_size, void* d_ws,
                              size_t ws_size, hipStream_t stream) {
  const float* x = (const float*)d_in[0];
  const int* ei = (const int*)d_in[1];
  const float* Wl0 = (const float*)d_in[2];
  const float* bl0 = (const float*)d_in[3];
  const float* Wr0 = (const float*)d_in[4];
  const float* Wl1 = (const float*)d_in[5];
  const float* bl1 = (const float*)d_in[6];
  const float* Wr1 = (const float*)d_in[7];
  float* out = (float*)d_out;

  const int N = N_NODES;

  // Workspace:
  //   aggx : N*64 f32
  //   bufB : h1 [N,32] + hr1 [N,32]
  //   deg[N], bcnt[1024], bbase[1025], bcursor[1024], rowptr[N+1], ebuf[E]
  float* aggx = (float*)d_ws;
  float* bufB = aggx + (size_t)N * 64;
  unsigned* deg = (unsigned*)(bufB + (size_t)N * 64);
  unsigned* bcnt = deg + N;
  unsigned* bbase = bcnt + NWIN;
  unsigned* bcursor = bbase + (NWIN + 1);
  unsigned* rowptr = bcursor + NWIN;
  unsigned* ebuf = rowptr + (N + 1);
  float* h1 = bufB;
  float* hr1 = bufB + (size_t)N * 32;

  hipMemsetAsync(bcnt, 0, NWIN * sizeof(unsigned), stream);

  const dim3 blk(256);

  // ---- edge bucketing + per-window counting sort -> CSR (both layers) ----
  bucket_count<<<CB, blk, 0, stream>>>(ei, bcnt);
  bucket_scan<<<1, NWIN, 0, stream>>>(bcnt, bbase, bcursor);
  bucket_fill<<<FB, blk, 0, stream>>>(ei, bcursor, ebuf);
  win_sort<<<NWIN, blk, 0, stream>>>(ebuf, bbase, rowptr, deg);

  // ---- layer-0 aggregation: aggx = mean(x[src]) ----
  gather_comb<64, false><<<(N * 64 + 255) / 256, blk, 0, stream>>>(
      x, rowptr, ebuf, nullptr, aggx);

  // ---- fused GEMMs: h in LDS; emits h1 = h@Wl1.T+bl1, hr1 = h@Wr1.T ----
  gemm01_kernel<<<NTILES, blk, 0, stream>>>(x, aggx, Wr0, Wl0, bl0, deg, Wl1,
                                            bl1, Wr1, h1, hr1);

  // ---- layer-1 aggregation + combine: out = mean(h1[src]) + hr1 ----
  gather_comb<32, true><<<(N * 64 + 255) / 256, blk, 0, stream>>>(
      h1, rowptr, ebuf, hr1, out);
}